// Round 1
// baseline (2620.546 us; speedup 1.0000x reference)
//
#include <hip/hip_runtime.h>

#define DT_C 0.1f

__device__ __forceinline__ float sigm(float z)  { return 1.0f / (1.0f + __expf(-z)); }
__device__ __forceinline__ float tanhf_(float z){ return 2.0f / (1.0f + __expf(-2.0f * z)) - 1.0f; }

// B=256, S=2048, I=1, H=128, O=1
// Grid: 256 blocks (one per batch row). Block: 512 threads, t = j*4 + ks.
// Thread (j,ks) holds W_att/W_rec/W_acc rows j, k-slice [ks*32, ks*32+32) in VGPRs.
// k-partials reduced across the 4 consecutive lanes via shfl_xor(1), shfl_xor(2).
__global__ __launch_bounds__(512, 2)
void clnm_kernel(const float* __restrict__ x,      // [256,2048]
                 const float* __restrict__ W_in,   // [128,1]
                 const float* __restrict__ b_in,   // [128]
                 const float* __restrict__ W_rec,  // [128,128]
                 const float* __restrict__ b_rec,  // [128]
                 const float* __restrict__ tau,    // [128]
                 const float* __restrict__ W_att,  // [128,128]
                 const float* __restrict__ b_att,  // [128]
                 const float* __restrict__ W_ev,   // [1,2]
                 const float* __restrict__ b_ev,   // [1]
                 const float* __restrict__ W_acc,  // [128,128]
                 const float* __restrict__ b_acc,  // [128]
                 const float* __restrict__ W_out,  // [1,128]
                 const float* __restrict__ b_out,  // [1]
                 float* __restrict__ out,          // [256]
                 float* __restrict__ out_ew)       // [256,2048]
{
    const int t  = threadIdx.x;
    const int j  = t >> 2;
    const int ks = t & 3;
    const int r  = blockIdx.x;

    __shared__ __align__(16) float x_lds[2048];
    __shared__ __align__(16) float h_lds[128];
    __shared__ __align__(16) float hatt_lds[128];
    __shared__ float red[8];

    // Stage this row's x into LDS (coalesced float4).
    ((float4*)x_lds)[t] = ((const float4*)(x + (size_t)r * 2048))[t];

    // Load persistent weight slices into registers.
    // W[j][ks*32 + i] = W.flat[32*t + i]  -> contiguous float4 chunks per thread.
    float wA[32], wR[32], wC[32];
    {
        const float4* a4 = (const float4*)W_att;
        const float4* r4 = (const float4*)W_rec;
        const float4* c4 = (const float4*)W_acc;
#pragma unroll
        for (int i = 0; i < 8; ++i) {
            float4 v;
            v = a4[t * 8 + i]; wA[4*i]=v.x; wA[4*i+1]=v.y; wA[4*i+2]=v.z; wA[4*i+3]=v.w;
            v = r4[t * 8 + i]; wR[4*i]=v.x; wR[4*i+1]=v.y; wR[4*i+2]=v.z; wR[4*i+3]=v.w;
            v = c4[t * 8 + i]; wC[4*i]=v.x; wC[4*i+1]=v.y; wC[4*i+2]=v.z; wC[4*i+3]=v.w;
        }
    }

    const float w_in_j  = W_in[j];
    const float b_in_j  = b_in[j];
    const float b_att_j = b_att[j];
    const float b_rec_j = b_rec[j];
    const float b_acc_j = b_acc[j];
    const float wout_j  = W_out[j];
    float tc = fminf(fmaxf(tau[j], 0.1f), 10.0f);
    const float tinv = 1.0f / tc;
    const float wev0 = W_ev[0], wev1 = W_ev[1], bev = b_ev[0], bout = b_out[0];

    if (t < 128) h_lds[t] = 0.0f;
    __syncthreads();

    const float4* h4  = (const float4*)h_lds;
    const float4* ha4 = (const float4*)hatt_lds;
    const int cb = ks * 8;

    float hj = 0.0f, accv = 0.0f, xprev = 0.0f;

    // Register-cached h-slice (h_t[ks*32..+32]); reused by ACC(t-1) and ATT(t).
    float4 hv[8];
#pragma unroll
    for (int i = 0; i < 8; ++i) hv[i] = h4[cb + i];   // zeros

    for (int s = 0; s < 2048; ++s) {
        const float xt = x_lds[s];
        const float ew = (s == 0) ? 0.0f : sigm(wev0 * xt + wev1 * xprev + bev);
        xprev = xt;
        if (t == 0) out_ew[(size_t)r * 2048 + s] = ew;
        const float ic = tanhf_(xt * w_in_j + b_in_j);

        // ---- ATT: att = sigmoid(h @ W_att^T + b_att) ----
        float s0 = 0.f, s1 = 0.f, s2 = 0.f, s3 = 0.f;
#pragma unroll
        for (int i = 0; i < 8; ++i) {
            s0 = fmaf(wA[4*i+0], hv[i].x, s0);
            s1 = fmaf(wA[4*i+1], hv[i].y, s1);
            s2 = fmaf(wA[4*i+2], hv[i].z, s2);
            s3 = fmaf(wA[4*i+3], hv[i].w, s3);
        }
        float sum = (s0 + s1) + (s2 + s3);
        sum += __shfl_xor(sum, 1);
        sum += __shfl_xor(sum, 2);
        const float att  = sigm(sum + b_att_j);
        const float hatt = hj * att;
        if (ks == 0) hatt_lds[j] = hatt;
        __syncthreads();   // A: hatt visible; all reads of h_t (regs) already done

        // ---- REC: rec = tanh((h*att) @ W_rec^T + b_rec) ----
        s0 = 0.f; s1 = 0.f; s2 = 0.f; s3 = 0.f;
#pragma unroll
        for (int i = 0; i < 8; ++i) {
            float4 av = ha4[cb + i];
            s0 = fmaf(wR[4*i+0], av.x, s0);
            s1 = fmaf(wR[4*i+1], av.y, s1);
            s2 = fmaf(wR[4*i+2], av.z, s2);
            s3 = fmaf(wR[4*i+3], av.w, s3);
        }
        sum = (s0 + s1) + (s2 + s3);
        sum += __shfl_xor(sum, 1);
        sum += __shfl_xor(sum, 2);
        const float rec  = tanhf_(sum + b_rec_j);
        // h_new = h + DT*(1+ew)/tau * (ic + rec - h)
        const float hnew = fmaf(DT_C * (1.0f + ew) * tinv, (ic + rec) - hj, hj);
        if (ks == 0) h_lds[j] = hnew;
        hj = hnew;
        __syncthreads();   // B: h_{t+1} visible

        // Reload register h-slice (h_{t+1}); used by ACC now and ATT next step.
#pragma unroll
        for (int i = 0; i < 8; ++i) hv[i] = h4[cb + i];

        // ---- ACC: acc = 0.9 acc + 0.1 tanh(h_new @ W_acc^T + b_acc) * ew ----
        s0 = 0.f; s1 = 0.f; s2 = 0.f; s3 = 0.f;
#pragma unroll
        for (int i = 0; i < 8; ++i) {
            s0 = fmaf(wC[4*i+0], hv[i].x, s0);
            s1 = fmaf(wC[4*i+1], hv[i].y, s1);
            s2 = fmaf(wC[4*i+2], hv[i].z, s2);
            s3 = fmaf(wC[4*i+3], hv[i].w, s3);
        }
        sum = (s0 + s1) + (s2 + s3);
        sum += __shfl_xor(sum, 1);
        sum += __shfl_xor(sum, 2);
        const float av = tanhf_(sum + b_acc_j);
        accv = fmaf(0.1f * ew, av, 0.9f * accv);
    }

    // ---- Output: out[r] = sum_j (h_f[j] + acc_f[j]) * W_out[j] + b_out ----
    float val = (ks == 0) ? (hj + accv) * wout_j : 0.0f;
#pragma unroll
    for (int m = 1; m < 64; m <<= 1) val += __shfl_xor(val, m);
    const int wave = t >> 6, lane = t & 63;
    if (lane == 0) red[wave] = val;
    __syncthreads();
    if (t == 0) {
        float o = bout;
#pragma unroll
        for (int w = 0; w < 8; ++w) o += red[w];
        out[r] = o;
    }
}

extern "C" void kernel_launch(void* const* d_in, const int* in_sizes, int n_in,
                              void* d_out, int out_size, void* d_ws, size_t ws_size,
                              hipStream_t stream) {
    const float* x     = (const float*)d_in[0];
    const float* W_in  = (const float*)d_in[1];
    const float* b_in  = (const float*)d_in[2];
    const float* W_rec = (const float*)d_in[3];
    const float* b_rec = (const float*)d_in[4];
    const float* tau   = (const float*)d_in[5];
    const float* W_att = (const float*)d_in[6];
    const float* b_att = (const float*)d_in[7];
    const float* W_ev  = (const float*)d_in[8];
    const float* b_ev  = (const float*)d_in[9];
    const float* W_acc = (const float*)d_in[10];
    const float* b_acc = (const float*)d_in[11];
    const float* W_out = (const float*)d_in[12];
    const float* b_out = (const float*)d_in[13];

    float* out    = (float*)d_out;        // [256,1]
    float* out_ew = out + 256;            // [256,2048]

    clnm_kernel<<<256, 512, 0, stream>>>(x, W_in, b_in, W_rec, b_rec, tau,
                                         W_att, b_att, W_ev, b_ev,
                                         W_acc, b_acc, W_out, b_out,
                                         out, out_ew);
}